// Round 6
// baseline (122.165 us; speedup 1.0000x reference)
//
#include <hip/hip_runtime.h>
#include <math.h>

#define T_DIM 4096
#define H_DIM 2048
#define N_DIM 1024
#define N2    2048           // 2*N (concat re/im) == H
#define KK    2048           // K of both GEMMs
#define CHUNK 64
#define NCHUNK (T_DIM / CHUNK)
#define NT    (KK / 64)      // 32 K-tiles of BK=64

using u16    = unsigned short;
using u16x4  = __attribute__((ext_vector_type(4))) u16;
using bf16x8 = __attribute__((ext_vector_type(8))) short;
using f32x4  = __attribute__((ext_vector_type(4))) float;

typedef const __attribute__((address_space(1))) u16 glob_u16;
typedef __attribute__((address_space(3))) u16 lds_u16;

__device__ inline void gload16(const u16* g, u16* l) {
    // async global->LDS: per-lane global src, wave-uniform LDS base + lane*16
    __builtin_amdgcn_global_load_lds((glob_u16*)g, (lds_u16*)l, 16, 0, 0);
}

__device__ inline u16 f2bf(float x) {   // RNE fp32->bf16
    unsigned u = __builtin_bit_cast(unsigned, x);
    u += 0x7fffu + ((u >> 16) & 1u);
    return (u16)(u >> 16);
}
__device__ inline float bf2f(u16 x) {
    return __builtin_bit_cast(float, (unsigned)x << 16);
}

// ---------------------------------------------------------------------------
// Conversion kernels
// ---------------------------------------------------------------------------
__global__ __launch_bounds__(256) void cvt_u_k(const float* __restrict__ X,
                                               u16* __restrict__ Y) {
    size_t i = ((size_t)blockIdx.x * 256 + threadIdx.x) * 4;
    float4 v = *(const float4*)(X + i);
    u16x4 o = { f2bf(v.x), f2bf(v.y), f2bf(v.z), f2bf(v.w) };
    *(u16x4*)(Y + i) = o;
}

__global__ __launch_bounds__(256) void cvt_b_k(const float* __restrict__ Bre,
                                               const float* __restrict__ Bim,
                                               const float* __restrict__ glog,
                                               u16* __restrict__ Bcat) {
    size_t i = ((size_t)blockIdx.x * 256 + threadIdx.x) * 4;
    int n = (int)(i >> 11);          // row in [0, 2048)
    size_t h = i & 2047;
    int nn = n & (N_DIM - 1);
    float g = expf(glog[nn]);
    const float* src = (n < N_DIM ? Bre : Bim) + (size_t)nn * H_DIM + h;
    float4 v = *(const float4*)src;
    u16x4 o = { f2bf(v.x * g), f2bf(v.y * g), f2bf(v.z * g), f2bf(v.w * g) };
    *(u16x4*)(Bcat + i) = o;
}

__global__ __launch_bounds__(256) void cvt_c_k(const float* __restrict__ Cre,
                                               const float* __restrict__ Cim,
                                               u16* __restrict__ Ccat) {
    size_t i = ((size_t)blockIdx.x * 256 + threadIdx.x) * 4;
    int hrow = (int)(i >> 11);
    int n = (int)(i & 2047);
    float sgn = 1.f;
    const float* src;
    if (n < N_DIM) src = Cre + (size_t)hrow * N_DIM + n;
    else { src = Cim + (size_t)hrow * N_DIM + (n - N_DIM); sgn = -1.f; }
    float4 v = *(const float4*)src;
    u16x4 o = { f2bf(v.x * sgn), f2bf(v.y * sgn), f2bf(v.z * sgn), f2bf(v.w * sgn) };
    *(u16x4*)(Ccat + i) = o;
}

// ---------------------------------------------------------------------------
// K-split bf16 NT GEMM.  BM=256 BN=128 BK=64, 512 thr = 8 waves:
// (wr 2 x wc 2 x kg 2), per-wave OUTPUT 128x64 over HALF of each K-tile
// (kg selects k in [kg*32, kg*32+32)).  8x4 frags of mfma_f32_16x16x32_bf16,
// acc = 128 VGPR.  LDS traffic per K-tile/CU: 96KB read + 48KB write
// (vs 128+64 at 64x64/wave) -> MFMA (1241cy) is now the critical resource.
// A triple-buffered (3x32KB, staged 2 ahead), B double-buffered (2x16KB,
// staged 1 ahead) = 128KB LDS.  One barrier + counted vmcnt(4) per K-tile.
// Epilogue: kg=1 waves dump acc via LDS, kg=0 adds + stores.
// LDS XOR-swizzle both-sides (pre-swizzled global src + swizzled read).
// EPI=1: C += D[col]*bf2f(Ubf[row][col])
// ---------------------------------------------------------------------------
template <int EPI>
__global__ __launch_bounds__(512, 2) void gemm_pipe(
    const u16* __restrict__ A, const u16* __restrict__ B,
    float* __restrict__ C, const float* __restrict__ D,
    const u16* __restrict__ Ubf)
{
    __shared__ u16 lds[65536];   // A bufs @ 0,16384,32768 ; B bufs @ 49152,+8192

    const int tid  = threadIdx.x;
    const int wave = tid >> 6, lane = tid & 63;
    // XCD-aware swizzle: 256 blocks, 8 XCDs -> each XCD gets 2 contiguous bm rows
    const int nbid = (blockIdx.x & 7) * 32 + (blockIdx.x >> 3);
    const int bm = nbid >> 4;                // 0..15
    const int bn = nbid & 15;                // 0..15
    const size_t row0 = (size_t)bm * 256;
    const size_t col0 = (size_t)bn * 128;
    const int kg = wave & 1;                 // K-half within each tile
    const int wc = (wave >> 1) & 1;          // output col half (64)
    const int wr = wave >> 2;                // output row half (128)
    const int fr = lane & 15, fq = lane >> 4;

    // staging: thread covers row (u*64 + tid>>3), source col-chunk pre-swizzled
    const int srow = tid >> 3;               // 0..63
    const int skc  = (tid & 7) ^ (srow & 7);
    const u16* aSrc = A + (row0 + srow) * KK + skc * 8;
    const u16* bSrc = B + (col0 + srow) * KK + skc * 8;

    // frag-read offsets (u16 indices); chunk = kg*4+fq, slot swizzled by row&7
    const int slot = ((kg * 4 + fq) ^ (fr & 7)) * 8;
    const int aOff = (wr * 128 + fr) * 64 + slot;   // + m*16*64
    const int bOff = (wc * 64 + fr) * 64 + slot;    // + n*16*64

    f32x4 acc[8][4] = {};

    auto STAGE_A = [&](int buf, int kt) {
#pragma unroll
        for (int u = 0; u < 4; ++u)
            gload16(aSrc + (size_t)u * 64 * KK + kt * 64,
                    &lds[buf * 16384 + u * 4096 + wave * 512]);
    };
    auto STAGE_B = [&](int buf, int kt) {
#pragma unroll
        for (int u = 0; u < 2; ++u)
            gload16(bSrc + (size_t)u * 64 * KK + kt * 64,
                    &lds[49152 + buf * 8192 + u * 4096 + wave * 512]);
    };

    // prologue: issue A(0), B(0), A(1) -> 10 loads; publish tile 0
    STAGE_A(0, 0); STAGE_B(0, 0); STAGE_A(1, 1);
    asm volatile("s_waitcnt vmcnt(4)" ::: "memory");
    __builtin_amdgcn_s_barrier();

    int a_cur = 0;                           // t % 3
    for (int t = 0; t < NT; ++t) {
        const u16* Ab = &lds[a_cur * 16384];
        const u16* Bb = &lds[49152 + (t & 1) * 8192];

        bf16x8 fb[4], fa[8];
#pragma unroll
        for (int n = 0; n < 4; ++n) fb[n] = *(const bf16x8*)&Bb[bOff + n * 1024];
#pragma unroll
        for (int m = 0; m < 8; ++m) fa[m] = *(const bf16x8*)&Ab[aOff + m * 1024];

        if (t + 1 < NT) STAGE_B((t + 1) & 1, t + 1);       // 2 gloads/wave
        if (t + 2 < NT) {
            int a_nxt = a_cur + 2; if (a_nxt >= 3) a_nxt -= 3;
            STAGE_A(a_nxt, t + 2);                         // 4 gloads/wave
        }

        __builtin_amdgcn_s_setprio(1);
#pragma unroll
        for (int m = 0; m < 8; ++m)
#pragma unroll
            for (int n = 0; n < 4; ++n)
                acc[m][n] = __builtin_amdgcn_mfma_f32_16x16x32_bf16(
                    fa[m], fb[n], acc[m][n], 0, 0, 0);
        __builtin_amdgcn_s_setprio(0);

        if (t + 1 < NT) {
            // publish tile t+1; A(t+2) may stay in flight (counted, never 0 mid-loop)
            if (t + 2 < NT) asm volatile("s_waitcnt vmcnt(4)" ::: "memory");
            else            asm volatile("s_waitcnt vmcnt(0)" ::: "memory");
            __builtin_amdgcn_s_barrier();
        }
        ++a_cur; if (a_cur == 3) a_cur = 0;
    }

    // ---- K-half merge through LDS (reuses staging space; all reads done) ----
    __builtin_amdgcn_s_barrier();
    const int pair = wr * 2 + wc;            // 0..3 -> 32KB slot each
    float* lf = (float*)lds;
    if (kg == 1) {
#pragma unroll
        for (int i = 0; i < 32; ++i)
            *(f32x4*)&lf[pair * 8192 + (i * 64 + lane) * 4] = acc[i >> 2][i & 3];
    }
    asm volatile("s_waitcnt lgkmcnt(0)" ::: "memory");
    __builtin_amdgcn_s_barrier();
    if (kg == 0) {
#pragma unroll
        for (int i = 0; i < 32; ++i) {
            f32x4 o = *(const f32x4*)&lf[pair * 8192 + (i * 64 + lane) * 4];
            acc[i >> 2][i & 3] += o;
        }
        // epilogue: C/D layout col=lane&15, row=(lane>>4)*4+reg  [m89/m91]
        const int crow = (int)row0 + wr * 128 + fq * 4;
        const int ccol = (int)col0 + wc * 64 + fr;
        float dc[4];
        if constexpr (EPI) {
#pragma unroll
            for (int n = 0; n < 4; ++n) dc[n] = D[ccol + n * 16];
        }
#pragma unroll
        for (int m = 0; m < 8; ++m)
#pragma unroll
            for (int n = 0; n < 4; ++n) {
                int cc = ccol + n * 16;
#pragma unroll
                for (int j = 0; j < 4; ++j) {
                    int r = crow + m * 16 + j;
                    size_t p = (size_t)r * N2 + cc;
                    float v = acc[m][n][j];
                    if constexpr (EPI) v += dc[n] * bf2f(Ubf[p]);
                    C[p] = v;
                }
            }
    }
}

// ---------------------------------------------------------------------------
// Scan, recompute scheme.  Bu layout [T, 2N]: re at col c, im at col c+N.
// pass 1: per-(chunk,chan) local carry only (read Bu once, no Bu writes)
// ---------------------------------------------------------------------------
__global__ __launch_bounds__(256) void carry_pass_k(const float* __restrict__ Bu,
                                                    const float* __restrict__ nu,
                                                    const float* __restrict__ theta,
                                                    float* __restrict__ car) {
    int idx = blockIdx.x * 256 + threadIdx.x;   // 0 .. NCHUNK*N-1
    int chan = idx & (N_DIM - 1);
    int chunk = idx >> 10;
    float a = expf(nu[chan]), b = expf(theta[chan]);
    float m = expf(-a), s, c;
    __sincosf(b, &s, &c);
    float lr = m * c, li = m * s;
    float hr = 0.f, hi = 0.f;
    size_t base = (size_t)chunk * CHUNK * N2 + chan;
    for (int i = 0; i < CHUNK; ++i) {
        size_t p = base + (size_t)i * N2;
        float br = Bu[p], bi = Bu[p + N_DIM];
        float nr = fmaf(lr, hr, fmaf(-li, hi, br));
        float ni = fmaf(lr, hi, fmaf(li, hr, bi));
        hr = nr; hi = ni;
    }
    car[(size_t)chunk * N2 + chan] = hr;
    car[(size_t)chunk * N2 + N_DIM + chan] = hi;
}

// pass 2: combine carries across chunks (per channel, lambda^CHUNK closed form)
__global__ __launch_bounds__(256) void scan_carry_k(float* __restrict__ car,
                                                    const float* __restrict__ nu,
                                                    const float* __restrict__ theta) {
    __shared__ float sR[NCHUNK][65], sI[NCHUNK][65];
    int tid = threadIdx.x;
    int chan0 = blockIdx.x * 64;
    for (int i = tid; i < NCHUNK * 64; i += 256) {
        int ck = i >> 6, c = i & 63;
        sR[ck][c] = car[(size_t)ck * N2 + chan0 + c];
        sI[ck][c] = car[(size_t)ck * N2 + N_DIM + chan0 + c];
    }
    __syncthreads();
    if (tid < 64) {
        int chan = chan0 + tid;
        float a = expf(nu[chan]), b = expf(theta[chan]);
        float m = expf(-(float)CHUNK * a), s, c;
        __sincosf((float)CHUNK * b, &s, &c);
        float lr = m * c, li = m * s;
        float hr = sR[0][tid], hi = sI[0][tid];
        for (int ck = 1; ck < NCHUNK; ++ck) {
            float nr = fmaf(lr, hr, fmaf(-li, hi, sR[ck][tid]));
            float ni = fmaf(lr, hi, fmaf(li, hr, sI[ck][tid]));
            hr = nr; hi = ni;
            sR[ck][tid] = hr; sI[ck][tid] = hi;
        }
    }
    __syncthreads();
    for (int i = tid; i < NCHUNK * 64; i += 256) {
        int ck = i >> 6, c = i & 63;
        car[(size_t)ck * N2 + chan0 + c] = sR[ck][c];
        car[(size_t)ck * N2 + N_DIM + chan0 + c] = sI[ck][c];
    }
}

// pass 3: recompute local scan seeded with combined carry, write bf16 h
__global__ __launch_bounds__(256) void scan_out_k(const float* __restrict__ Bu,
                                                  const float* __restrict__ car,
                                                  const float* __restrict__ nu,
                                                  const float* __restrict__ theta,
                                                  u16* __restrict__ Hbf) {
    int idx = blockIdx.x * 256 + threadIdx.x;   // 0 .. NCHUNK*N-1
    int chan = idx & (N_DIM - 1);
    int chunk = idx >> 10;
    float a = expf(nu[chan]), b = expf(theta[chan]);
    float m = expf(-a), s, c;
    __sincosf(b, &s, &c);
    float lr = m * c, li = m * s;
    float hr = 0.f, hi = 0.f;
    if (chunk > 0) {
        size_t cp = (size_t)(chunk - 1) * N2 + chan;
        hr = car[cp]; hi = car[cp + N_DIM];
    }
    size_t base = (size_t)chunk * CHUNK * N2 + chan;
    for (int i = 0; i < CHUNK; ++i) {
        size_t p = base + (size_t)i * N2;
        float br = Bu[p], bi = Bu[p + N_DIM];
        float nr = fmaf(lr, hr, fmaf(-li, hi, br));
        float ni = fmaf(lr, hi, fmaf(li, hr, bi));
        hr = nr; hi = ni;
        Hbf[p] = f2bf(hr);
        Hbf[p + N_DIM] = f2bf(hi);
    }
}

extern "C" void kernel_launch(void* const* d_in, const int* in_sizes, int n_in,
                              void* d_out, int out_size, void* d_ws, size_t ws_size,
                              hipStream_t stream) {
    const float* U     = (const float*)d_in[0];   // [T,H]
    const float* nu    = (const float*)d_in[1];   // [N]
    const float* theta = (const float*)d_in[2];   // [N]
    const float* glog  = (const float*)d_in[3];   // [N]
    const float* Bre   = (const float*)d_in[4];   // [N,H]
    const float* Bim   = (const float*)d_in[5];   // [N,H]
    const float* Cre   = (const float*)d_in[6];   // [H,N]
    const float* Cim   = (const float*)d_in[7];   // [H,N]
    const float* Dp    = (const float*)d_in[8];   // [H]
    float* Y = (float*)d_out;

    u16* Ubf  = (u16*)d_ws;                             // T*H       bf16
    u16* Bcat = Ubf + (size_t)T_DIM * H_DIM;            // 2N*H      bf16
    u16* Ccat = Bcat + (size_t)N2 * H_DIM;              // H*2N      bf16
    u16* Hbf  = Ccat + (size_t)H_DIM * N2;              // T*2N      bf16
    float* Bu = (float*)(Hbf + (size_t)T_DIM * N2);     // T*2N      f32
    float* car = Bu + (size_t)T_DIM * N2;               // NCHUNK*2N f32

    cvt_u_k<<<(T_DIM * H_DIM / 4) / 256, 256, 0, stream>>>(U, Ubf);
    cvt_b_k<<<((size_t)N2 * H_DIM / 4) / 256, 256, 0, stream>>>(Bre, Bim, glog, Bcat);
    cvt_c_k<<<((size_t)H_DIM * N2 / 4) / 256, 256, 0, stream>>>(Cre, Cim, Ccat);

    gemm_pipe<0><<<256, 512, 0, stream>>>(Ubf, Bcat, Bu, nullptr, nullptr);

    carry_pass_k<<<(NCHUNK * N_DIM) / 256, 256, 0, stream>>>(Bu, nu, theta, car);
    scan_carry_k<<<N_DIM / 64, 256, 0, stream>>>(car, nu, theta);
    scan_out_k<<<(NCHUNK * N_DIM) / 256, 256, 0, stream>>>(Bu, car, nu, theta, Hbf);

    gemm_pipe<1><<<256, 512, 0, stream>>>(Hbf, Ccat, Y, Dp, Ubf);
}

// Round 7
// 114.135 us; speedup vs baseline: 1.0704x; 1.0704x over previous
//
#include <hip/hip_runtime.h>
#include <math.h>

#define T_DIM 4096
#define H_DIM 2048
#define N_DIM 1024
#define N2    2048           // 2*N (concat re/im) == H
#define KK    2048           // K of both GEMMs
#define CHUNK 64
#define NCHUNK (T_DIM / CHUNK)
#define NT    (KK / 64)      // 32 K-tiles of BK=64

using u16    = unsigned short;
using u16x4  = __attribute__((ext_vector_type(4))) u16;
using bf16x8 = __attribute__((ext_vector_type(8))) short;
using f32x4  = __attribute__((ext_vector_type(4))) float;

typedef const __attribute__((address_space(1))) u16 glob_u16;
typedef __attribute__((address_space(3))) u16 lds_u16;

__device__ inline void gload16(const u16* g, u16* l) {
    // async global->LDS: per-lane global src, wave-uniform LDS base + lane*16
    __builtin_amdgcn_global_load_lds((glob_u16*)g, (lds_u16*)l, 16, 0, 0);
}

__device__ inline u16 f2bf(float x) {   // RNE fp32->bf16
    unsigned u = __builtin_bit_cast(unsigned, x);
    u += 0x7fffu + ((u >> 16) & 1u);
    return (u16)(u >> 16);
}
__device__ inline float bf2f(u16 x) {
    return __builtin_bit_cast(float, (unsigned)x << 16);
}

// ---------------------------------------------------------------------------
// Conversion kernels
// ---------------------------------------------------------------------------
__global__ __launch_bounds__(256) void cvt_u_k(const float* __restrict__ X,
                                               u16* __restrict__ Y) {
    size_t i = ((size_t)blockIdx.x * 256 + threadIdx.x) * 4;
    float4 v = *(const float4*)(X + i);
    u16x4 o = { f2bf(v.x), f2bf(v.y), f2bf(v.z), f2bf(v.w) };
    *(u16x4*)(Y + i) = o;
}

__global__ __launch_bounds__(256) void cvt_b_k(const float* __restrict__ Bre,
                                               const float* __restrict__ Bim,
                                               const float* __restrict__ glog,
                                               u16* __restrict__ Bcat) {
    size_t i = ((size_t)blockIdx.x * 256 + threadIdx.x) * 4;
    int n = (int)(i >> 11);          // row in [0, 2048)
    size_t h = i & 2047;
    int nn = n & (N_DIM - 1);
    float g = expf(glog[nn]);
    const float* src = (n < N_DIM ? Bre : Bim) + (size_t)nn * H_DIM + h;
    float4 v = *(const float4*)src;
    u16x4 o = { f2bf(v.x * g), f2bf(v.y * g), f2bf(v.z * g), f2bf(v.w * g) };
    *(u16x4*)(Bcat + i) = o;
}

__global__ __launch_bounds__(256) void cvt_c_k(const float* __restrict__ Cre,
                                               const float* __restrict__ Cim,
                                               u16* __restrict__ Ccat) {
    size_t i = ((size_t)blockIdx.x * 256 + threadIdx.x) * 4;
    int hrow = (int)(i >> 11);
    int n = (int)(i & 2047);
    float sgn = 1.f;
    const float* src;
    if (n < N_DIM) src = Cre + (size_t)hrow * N_DIM + n;
    else { src = Cim + (size_t)hrow * N_DIM + (n - N_DIM); sgn = -1.f; }
    float4 v = *(const float4*)src;
    u16x4 o = { f2bf(v.x * sgn), f2bf(v.y * sgn), f2bf(v.z * sgn), f2bf(v.w * sgn) };
    *(u16x4*)(Ccat + i) = o;
}

// ---------------------------------------------------------------------------
// Multi-block bf16 NT GEMM.  BM=BN=128, BK=64, 256 thr = 4 waves (2x2),
// per-wave 64x64 via 4x4 frags of mfma_f32_16x16x32_bf16.
// LDS = A 3-buf (48KB, staged 2 ahead) + B 2-buf (32KB, staged 1 ahead)
//     = 80KB exactly -> 2 blocks/CU (grid 512 = 2/CU): inter-block overlap
// hides barrier/vmcnt stalls (the m97 mechanism).  One barrier + counted
// vmcnt(4) per K-tile; frag ping-pong (reads fetch next phase's frags).
// LDS XOR-swizzle both-sides (pre-swizzled global src + swizzled read).
// EPI=0: store bf16 (u16) Bu.  EPI=1: store f32 Y += D[col]*bf2f(Ubf).
// ---------------------------------------------------------------------------
template <int EPI>
__global__ __launch_bounds__(256, 2) void gemm_pipe(
    const u16* __restrict__ A, const u16* __restrict__ B,
    void* __restrict__ Cout, const float* __restrict__ D,
    const u16* __restrict__ Ubf)
{
    __shared__ u16 lds[40960];   // A bufs @ 0,8192,16384 ; B bufs @ 24576,32768

    const int tid  = threadIdx.x;
    const int wave = tid >> 6, lane = tid & 63;
    // XCD swizzle: 512 blocks, 8 XCDs -> 64 contiguous tile-ids per XCD
    const int nbid = (blockIdx.x & 7) * 64 + (blockIdx.x >> 3);
    const int bm = nbid >> 4;                // 0..31
    const int bn = nbid & 15;                // 0..15
    const size_t row0 = (size_t)bm * 128;
    const size_t col0 = (size_t)bn * 128;
    const int wr = wave >> 1, wc = wave & 1; // 2x2 wave grid, per-wave 64x64
    const int fr = lane & 15, fq = lane >> 4;

    // staging: thread covers row (u*32 + tid>>3), source col-chunk pre-swizzled
    const int srow = tid >> 3;               // 0..31
    const int skc  = (tid & 7) ^ (srow & 7);
    const u16* aSrc = A + (row0 + srow) * KK + skc * 8;
    const u16* bSrc = B + (col0 + srow) * KK + skc * 8;

    // frag-read bases (u16 indices), swizzled: slot = (kk*4+fq) ^ (fr&7)
    const int aOff = (wr * 64 + fr) * 64;    // + m*1024 + swz
    const int bOff = (wc * 64 + fr) * 64;    // + n*1024 + swz
    const int swz0 = ((fq)     ^ (fr & 7)) * 8;
    const int swz1 = ((4 + fq) ^ (fr & 7)) * 8;

    f32x4 acc[4][4] = {};

    auto STAGE_A = [&](int buf, int kt) {
#pragma unroll
        for (int u = 0; u < 4; ++u)
            gload16(aSrc + (size_t)u * 32 * KK + kt * 64,
                    &lds[buf * 8192 + u * 2048 + wave * 512]);
    };
    auto STAGE_B = [&](int buf, int kt) {
#pragma unroll
        for (int u = 0; u < 4; ++u)
            gload16(bSrc + (size_t)u * 32 * KK + kt * 64,
                    &lds[24576 + buf * 8192 + u * 2048 + wave * 512]);
    };

    bf16x8 fa[4], fb[4], ga[4], gb[4];       // named ping-pong frag sets

    auto READ_F = [&](const u16* Ab, const u16* Bb, int swz) {
#pragma unroll
        for (int m = 0; m < 4; ++m) fa[m] = *(const bf16x8*)&Ab[aOff + m * 1024 + swz];
#pragma unroll
        for (int n = 0; n < 4; ++n) fb[n] = *(const bf16x8*)&Bb[bOff + n * 1024 + swz];
    };
    auto READ_G = [&](const u16* Ab, const u16* Bb, int swz) {
#pragma unroll
        for (int m = 0; m < 4; ++m) ga[m] = *(const bf16x8*)&Ab[aOff + m * 1024 + swz];
#pragma unroll
        for (int n = 0; n < 4; ++n) gb[n] = *(const bf16x8*)&Bb[bOff + n * 1024 + swz];
    };
    auto MFMA_F = [&]() {
        __builtin_amdgcn_s_setprio(1);
#pragma unroll
        for (int m = 0; m < 4; ++m)
#pragma unroll
            for (int n = 0; n < 4; ++n)
                acc[m][n] = __builtin_amdgcn_mfma_f32_16x16x32_bf16(
                    fa[m], fb[n], acc[m][n], 0, 0, 0);
        __builtin_amdgcn_s_setprio(0);
    };
    auto MFMA_G = [&]() {
        __builtin_amdgcn_s_setprio(1);
#pragma unroll
        for (int m = 0; m < 4; ++m)
#pragma unroll
            for (int n = 0; n < 4; ++n)
                acc[m][n] = __builtin_amdgcn_mfma_f32_16x16x32_bf16(
                    ga[m], gb[n], acc[m][n], 0, 0, 0);
        __builtin_amdgcn_s_setprio(0);
    };

    // prologue: A(0), B(0), A(1) -> 12 loads; publish tile 0; preload f
    STAGE_A(0, 0); STAGE_B(0, 0); STAGE_A(1, 1);
    asm volatile("s_waitcnt vmcnt(4)" ::: "memory");
    __builtin_amdgcn_s_barrier();
    READ_F(&lds[0], &lds[24576], swz0);

    int a_cur = 0;                           // t % 3
    for (int t = 0; t < NT; ++t) {
        const u16* Ab = &lds[a_cur * 8192];
        const u16* Bb = &lds[24576 + (t & 1) * 8192];

        if (t + 1 < NT) STAGE_B((t + 1) & 1, t + 1);       // 4 gloads/wave
        MFMA_F();                                          // phase 0 (kk=0)
        if (t + 2 < NT) {
            int a_nxt = a_cur + 2; if (a_nxt >= 3) a_nxt -= 3;
            STAGE_A(a_nxt, t + 2);                         // 4 gloads/wave
        }
        READ_G(Ab, Bb, swz1);                              // frags for phase 1
        MFMA_G();                                          // phase 1 (kk=1)

        if (t + 1 < NT) {
            // publish tile t+1; A(t+2) may stay in flight (never 0 mid-loop)
            if (t + 2 < NT) asm volatile("s_waitcnt vmcnt(4)" ::: "memory");
            else            asm volatile("s_waitcnt vmcnt(0)" ::: "memory");
            __builtin_amdgcn_s_barrier();
            int a_n = a_cur + 1; if (a_n == 3) a_n = 0;
            READ_F(&lds[a_n * 8192], &lds[24576 + ((t + 1) & 1) * 8192], swz0);
        }
        ++a_cur; if (a_cur == 3) a_cur = 0;
    }

    // epilogue: C/D layout col=lane&15, row=(lane>>4)*4+reg  [m89/m91]
    const int crow = (int)row0 + wr * 64 + fq * 4;
    const int ccol = (int)col0 + wc * 64 + fr;
    float dc[4];
    if constexpr (EPI) {
#pragma unroll
        for (int n = 0; n < 4; ++n) dc[n] = D[ccol + n * 16];
    }
#pragma unroll
    for (int m = 0; m < 4; ++m)
#pragma unroll
        for (int n = 0; n < 4; ++n) {
            int cc = ccol + n * 16;
#pragma unroll
            for (int j = 0; j < 4; ++j) {
                int r = crow + m * 16 + j;
                size_t p = (size_t)r * N2 + cc;
                float v = acc[m][n][j];
                if constexpr (EPI)
                    ((float*)Cout)[p] = v + dc[n] * bf2f(Ubf[p]);
                else
                    ((u16*)Cout)[p] = f2bf(v);
            }
        }
}

// ---------------------------------------------------------------------------
// Scan (recompute scheme) over bf16 Bu, layout [T, 2N]: re at c, im at c+N.
// pass 1: per-(chunk,chan) local carry only (read Bu once)
// ---------------------------------------------------------------------------
__global__ __launch_bounds__(256) void carry_pass_k(const u16* __restrict__ Bu,
                                                    const float* __restrict__ nu,
                                                    const float* __restrict__ theta,
                                                    float* __restrict__ car) {
    int idx = blockIdx.x * 256 + threadIdx.x;   // 0 .. NCHUNK*N-1
    int chan = idx & (N_DIM - 1);
    int chunk = idx >> 10;
    float a = expf(nu[chan]), b = expf(theta[chan]);
    float m = expf(-a), s, c;
    __sincosf(b, &s, &c);
    float lr = m * c, li = m * s;
    float hr = 0.f, hi = 0.f;
    size_t base = (size_t)chunk * CHUNK * N2 + chan;
    for (int i = 0; i < CHUNK; ++i) {
        size_t p = base + (size_t)i * N2;
        float br = bf2f(Bu[p]), bi = bf2f(Bu[p + N_DIM]);
        float nr = fmaf(lr, hr, fmaf(-li, hi, br));
        float ni = fmaf(lr, hi, fmaf(li, hr, bi));
        hr = nr; hi = ni;
    }
    car[(size_t)chunk * N2 + chan] = hr;
    car[(size_t)chunk * N2 + N_DIM + chan] = hi;
}

// pass 2: combine carries across chunks (per channel, lambda^CHUNK closed form)
__global__ __launch_bounds__(256) void scan_carry_k(float* __restrict__ car,
                                                    const float* __restrict__ nu,
                                                    const float* __restrict__ theta) {
    __shared__ float sR[NCHUNK][65], sI[NCHUNK][65];
    int tid = threadIdx.x;
    int chan0 = blockIdx.x * 64;
    for (int i = tid; i < NCHUNK * 64; i += 256) {
        int ck = i >> 6, c = i & 63;
        sR[ck][c] = car[(size_t)ck * N2 + chan0 + c];
        sI[ck][c] = car[(size_t)ck * N2 + N_DIM + chan0 + c];
    }
    __syncthreads();
    if (tid < 64) {
        int chan = chan0 + tid;
        float a = expf(nu[chan]), b = expf(theta[chan]);
        float m = expf(-(float)CHUNK * a), s, c;
        __sincosf((float)CHUNK * b, &s, &c);
        float lr = m * c, li = m * s;
        float hr = sR[0][tid], hi = sI[0][tid];
        for (int ck = 1; ck < NCHUNK; ++ck) {
            float nr = fmaf(lr, hr, fmaf(-li, hi, sR[ck][tid]));
            float ni = fmaf(lr, hi, fmaf(li, hr, sI[ck][tid]));
            hr = nr; hi = ni;
            sR[ck][tid] = hr; sI[ck][tid] = hi;
        }
    }
    __syncthreads();
    for (int i = tid; i < NCHUNK * 64; i += 256) {
        int ck = i >> 6, c = i & 63;
        car[(size_t)ck * N2 + chan0 + c] = sR[ck][c];
        car[(size_t)ck * N2 + N_DIM + chan0 + c] = sI[ck][c];
    }
}

// pass 3: recompute local scan seeded with combined carry, write bf16 h
__global__ __launch_bounds__(256) void scan_out_k(const u16* __restrict__ Bu,
                                                  const float* __restrict__ car,
                                                  const float* __restrict__ nu,
                                                  const float* __restrict__ theta,
                                                  u16* __restrict__ Hbf) {
    int idx = blockIdx.x * 256 + threadIdx.x;   // 0 .. NCHUNK*N-1
    int chan = idx & (N_DIM - 1);
    int chunk = idx >> 10;
    float a = expf(nu[chan]), b = expf(theta[chan]);
    float m = expf(-a), s, c;
    __sincosf(b, &s, &c);
    float lr = m * c, li = m * s;
    float hr = 0.f, hi = 0.f;
    if (chunk > 0) {
        size_t cp = (size_t)(chunk - 1) * N2 + chan;
        hr = car[cp]; hi = car[cp + N_DIM];
    }
    size_t base = (size_t)chunk * CHUNK * N2 + chan;
    for (int i = 0; i < CHUNK; ++i) {
        size_t p = base + (size_t)i * N2;
        float br = bf2f(Bu[p]), bi = bf2f(Bu[p + N_DIM]);
        float nr = fmaf(lr, hr, fmaf(-li, hi, br));
        float ni = fmaf(lr, hi, fmaf(li, hr, bi));
        hr = nr; hi = ni;
        Hbf[p] = f2bf(hr);
        Hbf[p + N_DIM] = f2bf(hi);
    }
}

extern "C" void kernel_launch(void* const* d_in, const int* in_sizes, int n_in,
                              void* d_out, int out_size, void* d_ws, size_t ws_size,
                              hipStream_t stream) {
    const float* U     = (const float*)d_in[0];   // [T,H]
    const float* nu    = (const float*)d_in[1];   // [N]
    const float* theta = (const float*)d_in[2];   // [N]
    const float* glog  = (const float*)d_in[3];   // [N]
    const float* Bre   = (const float*)d_in[4];   // [N,H]
    const float* Bim   = (const float*)d_in[5];   // [N,H]
    const float* Cre   = (const float*)d_in[6];   // [H,N]
    const float* Cim   = (const float*)d_in[7];   // [H,N]
    const float* Dp    = (const float*)d_in[8];   // [H]
    float* Y = (float*)d_out;

    u16* Ubf  = (u16*)d_ws;                             // T*H       bf16
    u16* Bcat = Ubf + (size_t)T_DIM * H_DIM;            // 2N*H      bf16
    u16* Ccat = Bcat + (size_t)N2 * H_DIM;              // H*2N      bf16
    u16* Hbf  = Ccat + (size_t)H_DIM * N2;              // T*2N      bf16
    u16* Bu   = Hbf + (size_t)T_DIM * N2;               // T*2N      bf16
    float* car = (float*)(Bu + (size_t)T_DIM * N2);     // NCHUNK*2N f32

    cvt_u_k<<<(T_DIM * H_DIM / 4) / 256, 256, 0, stream>>>(U, Ubf);
    cvt_b_k<<<((size_t)N2 * H_DIM / 4) / 256, 256, 0, stream>>>(Bre, Bim, glog, Bcat);
    cvt_c_k<<<((size_t)H_DIM * N2 / 4) / 256, 256, 0, stream>>>(Cre, Cim, Ccat);

    gemm_pipe<0><<<512, 256, 0, stream>>>(Ubf, Bcat, (void*)Bu, nullptr, nullptr);

    carry_pass_k<<<(NCHUNK * N_DIM) / 256, 256, 0, stream>>>(Bu, nu, theta, car);
    scan_carry_k<<<N_DIM / 64, 256, 0, stream>>>(car, nu, theta);
    scan_out_k<<<(NCHUNK * N_DIM) / 256, 256, 0, stream>>>(Bu, car, nu, theta, Hbf);

    gemm_pipe<1><<<512, 256, 0, stream>>>(Hbf, Ccat, (void*)Y, Dp, Ubf);
}

// Round 8
// 111.557 us; speedup vs baseline: 1.0951x; 1.0231x over previous
//
#include <hip/hip_runtime.h>
#include <math.h>

#define T_DIM 4096
#define H_DIM 2048
#define N_DIM 1024
#define N2    2048           // 2*N (concat re/im) == H
#define KK    2048           // K of both GEMMs
#define CHUNK 64
#define NCHUNK (T_DIM / CHUNK)
#define NT    (KK / 64)      // 32 K-tiles of BK=64

using u16    = unsigned short;
using u16x4  = __attribute__((ext_vector_type(4))) u16;
using bf16x8 = __attribute__((ext_vector_type(8))) short;
using f32x4  = __attribute__((ext_vector_type(4))) float;

typedef const __attribute__((address_space(1))) u16 glob_u16;
typedef __attribute__((address_space(3))) u16 lds_u16;

__device__ inline void gload16(const u16* g, u16* l) {
    // async global->LDS: per-lane global src, wave-uniform LDS base + lane*16
    __builtin_amdgcn_global_load_lds((glob_u16*)g, (lds_u16*)l, 16, 0, 0);
}

__device__ inline u16 f2bf(float x) {   // RNE fp32->bf16
    unsigned u = __builtin_bit_cast(unsigned, x);
    u += 0x7fffu + ((u >> 16) & 1u);
    return (u16)(u >> 16);
}
__device__ inline float bf2f(u16 x) {
    return __builtin_bit_cast(float, (unsigned)x << 16);
}

// ---------------------------------------------------------------------------
// Merged conversion kernel: blockIdx ranges -> U / Bcat / Ccat regions
//   [0,8192)      : Ubf  = bf16(U)                     8M elems
//   [8192,12288)  : Bcat = bf16(gamma*B) interleaved?  (plain concat, as before)
//   [12288,16384) : Ccat = bf16([Cre | -Cim])
// ---------------------------------------------------------------------------
__global__ __launch_bounds__(256) void cvt_all_k(
    const float* __restrict__ U, const float* __restrict__ Bre,
    const float* __restrict__ Bim, const float* __restrict__ glog,
    const float* __restrict__ Cre, const float* __restrict__ Cim,
    u16* __restrict__ Ubf, u16* __restrict__ Bcat, u16* __restrict__ Ccat)
{
    int bid = blockIdx.x;
    if (bid < 8192) {
        size_t i = ((size_t)bid * 256 + threadIdx.x) * 4;
        float4 v = *(const float4*)(U + i);
        u16x4 o = { f2bf(v.x), f2bf(v.y), f2bf(v.z), f2bf(v.w) };
        *(u16x4*)(Ubf + i) = o;
    } else if (bid < 12288) {
        size_t i = ((size_t)(bid - 8192) * 256 + threadIdx.x) * 4;
        int n = (int)(i >> 11);
        size_t h = i & 2047;
        int nn = n & (N_DIM - 1);
        float g = expf(glog[nn]);
        const float* src = (n < N_DIM ? Bre : Bim) + (size_t)nn * H_DIM + h;
        float4 v = *(const float4*)src;
        u16x4 o = { f2bf(v.x * g), f2bf(v.y * g), f2bf(v.z * g), f2bf(v.w * g) };
        *(u16x4*)(Bcat + i) = o;
    } else {
        size_t i = ((size_t)(bid - 12288) * 256 + threadIdx.x) * 4;
        int hrow = (int)(i >> 11);
        int n = (int)(i & 2047);
        float sgn = 1.f;
        const float* src;
        if (n < N_DIM) src = Cre + (size_t)hrow * N_DIM + n;
        else { src = Cim + (size_t)hrow * N_DIM + (n - N_DIM); sgn = -1.f; }
        float4 v = *(const float4*)src;
        u16x4 o = { f2bf(v.x * sgn), f2bf(v.y * sgn), f2bf(v.z * sgn), f2bf(v.w * sgn) };
        *(u16x4*)(Ccat + i) = o;
    }
}

// ---------------------------------------------------------------------------
// High-occupancy K-split bf16 NT GEMM.
// BM=BN=128, BK=64, 512 thr = 8 waves (wr2 x wc2 x kg2); per-wave 64x64 over
// its K-half (k in [kg*32, kg*32+32)); 4x4 frags of mfma_f32_16x16x32_bf16,
// acc 64 VGPR + frags 32 -> target <=128 VGPR => 2 blocks/CU x 8 waves
// = 16 waves/CU = 4/SIMD (latency hiding via TLP).
// LDS = A 3-buf (48KB, staged 2 ahead) + B 2-buf (32KB, 1 ahead) = 80KB
// -> exactly 2 blocks/CU.  One barrier + counted vmcnt(2) per K-tile.
// Frag reads prefetched right after the boundary barrier.
// K-half merge via LDS epilogue (kg=1 dumps, kg=0 adds+stores; R6-verified).
// LDS XOR-swizzle both-sides (pre-swizzled global src + swizzled read).
// EPI=0: store bf16 Bu.  EPI=1: store f32 Y = acc + D[col]*bf2f(Ubf).
// ---------------------------------------------------------------------------
template <int EPI>
__global__ __launch_bounds__(512, 4) void gemm_pipe(
    const u16* __restrict__ A, const u16* __restrict__ B,
    void* __restrict__ Cout, const float* __restrict__ D,
    const u16* __restrict__ Ubf)
{
    __shared__ u16 lds[40960];   // A bufs @ 0,8192,16384 ; B bufs @ 24576,32768

    const int tid  = threadIdx.x;
    const int wave = tid >> 6, lane = tid & 63;
    // XCD swizzle: 512 blocks, 8 XCDs -> 64 contiguous tile-ids per XCD
    const int nbid = (blockIdx.x & 7) * 64 + (blockIdx.x >> 3);
    const int bm = nbid >> 4;                // 0..31
    const int bn = nbid & 15;                // 0..15
    const size_t row0 = (size_t)bm * 128;
    const size_t col0 = (size_t)bn * 128;
    const int kg = wave & 1;                 // K-half within each tile
    const int wc = (wave >> 1) & 1;          // output col half (64)
    const int wr = wave >> 2;                // output row half (64)
    const int fr = lane & 15, fq = lane >> 4;

    // staging: issue (wave,u) covers rows wave*16+u*8+(lane>>3), slot lane&7.
    // source chunk pre-swizzled: chunk = (lane&7) ^ ((lane>>3)&7)
    const int srow = wave * 16 + (lane >> 3);
    const int skc  = (lane & 7) ^ ((lane >> 3) & 7);
    const u16* aSrc = A + (row0 + srow) * KK + skc * 8;
    const u16* bSrc = B + (col0 + srow) * KK + skc * 8;
    const int stOff = wave * 1024;           // + u*512 (u16), HW adds lane*8

    // frag-read bases (u16), swizzled: slot = (kg*4+fq) ^ (fr&7)
    const int slot8 = ((kg * 4 + fq) ^ (fr & 7)) * 8;
    const int aOff = (wr * 64 + fr) * 64 + slot8;   // + m*1024
    const int bOff = (wc * 64 + fr) * 64 + slot8;   // + n*1024

    f32x4 acc[4][4] = {};

    auto STAGE_A = [&](int buf, int kt) {
        gload16(aSrc + kt * 64,            &lds[buf * 8192 + stOff]);
        gload16(aSrc + 8 * KK + kt * 64,   &lds[buf * 8192 + stOff + 512]);
    };
    auto STAGE_B = [&](int buf, int kt) {
        gload16(bSrc + kt * 64,            &lds[24576 + buf * 8192 + stOff]);
        gload16(bSrc + 8 * KK + kt * 64,   &lds[24576 + buf * 8192 + stOff + 512]);
    };

    bf16x8 fa[4], fb[4];
    auto READ_F = [&](const u16* Ab, const u16* Bb) {
#pragma unroll
        for (int m = 0; m < 4; ++m) fa[m] = *(const bf16x8*)&Ab[aOff + m * 1024];
#pragma unroll
        for (int n = 0; n < 4; ++n) fb[n] = *(const bf16x8*)&Bb[bOff + n * 1024];
    };

    // prologue: A(0) B(0) A(1) -> 6 gloads/thread; publish tile 0 (A(1) flies)
    STAGE_A(0, 0); STAGE_B(0, 0); STAGE_A(1, 1);
    asm volatile("s_waitcnt vmcnt(2)" ::: "memory");
    __builtin_amdgcn_s_barrier();
    READ_F(&lds[0], &lds[24576]);

    int a_cur = 0;                           // t % 3
    for (int t = 0; t < NT; ++t) {
        if (t + 1 < NT) STAGE_B((t + 1) & 1, t + 1);       // 2 gloads
        __builtin_amdgcn_s_setprio(1);
#pragma unroll
        for (int m = 0; m < 4; ++m)
#pragma unroll
            for (int n = 0; n < 4; ++n)
                acc[m][n] = __builtin_amdgcn_mfma_f32_16x16x32_bf16(
                    fa[m], fb[n], acc[m][n], 0, 0, 0);
        __builtin_amdgcn_s_setprio(0);
        if (t + 2 < NT) {
            int a_nxt = a_cur + 2; if (a_nxt >= 3) a_nxt -= 3;
            STAGE_A(a_nxt, t + 2);                         // 2 gloads
        }
        if (t + 1 < NT) {
            // publish tile t+1: A(t+1),B(t+1) landed; A(t+2) may fly
            if (t + 2 < NT) asm volatile("s_waitcnt vmcnt(2)" ::: "memory");
            else            asm volatile("s_waitcnt vmcnt(0)" ::: "memory");
            __builtin_amdgcn_s_barrier();
            int a_n = a_cur + 1; if (a_n == 3) a_n = 0;
            READ_F(&lds[a_n * 8192], &lds[24576 + ((t + 1) & 1) * 8192]);
        }
        ++a_cur; if (a_cur == 3) a_cur = 0;
    }

    // ---- K-half merge through LDS (reuses staging space; reads all done) ----
    __builtin_amdgcn_s_barrier();
    const int pair = wr * 2 + wc;            // 0..3, 16KB slot each
    float* lf = (float*)lds;
    if (kg == 1) {
#pragma unroll
        for (int i = 0; i < 16; ++i)
            *(f32x4*)&lf[pair * 4096 + i * 256 + lane * 4] = acc[i >> 2][i & 3];
    }
    asm volatile("s_waitcnt lgkmcnt(0)" ::: "memory");
    __builtin_amdgcn_s_barrier();
    if (kg == 0) {
#pragma unroll
        for (int i = 0; i < 16; ++i) {
            f32x4 o = *(const f32x4*)&lf[pair * 4096 + i * 256 + lane * 4];
            acc[i >> 2][i & 3] += o;
        }
        // epilogue: C/D layout col=lane&15, row=(lane>>4)*4+reg  [m89/m91]
        const int crow = (int)row0 + wr * 64 + fq * 4;
        const int ccol = (int)col0 + wc * 64 + fr;
        float dc[4];
        if constexpr (EPI) {
#pragma unroll
            for (int n = 0; n < 4; ++n) dc[n] = D[ccol + n * 16];
        }
#pragma unroll
        for (int m = 0; m < 4; ++m)
#pragma unroll
            for (int n = 0; n < 4; ++n) {
                int cc = ccol + n * 16;
#pragma unroll
                for (int j = 0; j < 4; ++j) {
                    int r = crow + m * 16 + j;
                    size_t p = (size_t)r * N2 + cc;
                    float v = acc[m][n][j];
                    if constexpr (EPI)
                        ((float*)Cout)[p] = v + dc[n] * bf2f(Ubf[p]);
                    else
                        ((u16*)Cout)[p] = f2bf(v);
                }
            }
    }
}

// ---------------------------------------------------------------------------
// Scan (recompute scheme) over bf16 Bu, layout [T, 2N]: re at c, im at c+N.
// ---------------------------------------------------------------------------
__global__ __launch_bounds__(256) void carry_pass_k(const u16* __restrict__ Bu,
                                                    const float* __restrict__ nu,
                                                    const float* __restrict__ theta,
                                                    float* __restrict__ car) {
    int idx = blockIdx.x * 256 + threadIdx.x;   // 0 .. NCHUNK*N-1
    int chan = idx & (N_DIM - 1);
    int chunk = idx >> 10;
    float a = expf(nu[chan]), b = expf(theta[chan]);
    float m = expf(-a), s, c;
    __sincosf(b, &s, &c);
    float lr = m * c, li = m * s;
    float hr = 0.f, hi = 0.f;
    size_t base = (size_t)chunk * CHUNK * N2 + chan;
    for (int i = 0; i < CHUNK; ++i) {
        size_t p = base + (size_t)i * N2;
        float br = bf2f(Bu[p]), bi = bf2f(Bu[p + N_DIM]);
        float nr = fmaf(lr, hr, fmaf(-li, hi, br));
        float ni = fmaf(lr, hi, fmaf(li, hr, bi));
        hr = nr; hi = ni;
    }
    car[(size_t)chunk * N2 + chan] = hr;
    car[(size_t)chunk * N2 + N_DIM + chan] = hi;
}

__global__ __launch_bounds__(256) void scan_carry_k(float* __restrict__ car,
                                                    const float* __restrict__ nu,
                                                    const float* __restrict__ theta) {
    __shared__ float sR[NCHUNK][65], sI[NCHUNK][65];
    int tid = threadIdx.x;
    int chan0 = blockIdx.x * 64;
    for (int i = tid; i < NCHUNK * 64; i += 256) {
        int ck = i >> 6, c = i & 63;
        sR[ck][c] = car[(size_t)ck * N2 + chan0 + c];
        sI[ck][c] = car[(size_t)ck * N2 + N_DIM + chan0 + c];
    }
    __syncthreads();
    if (tid < 64) {
        int chan = chan0 + tid;
        float a = expf(nu[chan]), b = expf(theta[chan]);
        float m = expf(-(float)CHUNK * a), s, c;
        __sincosf((float)CHUNK * b, &s, &c);
        float lr = m * c, li = m * s;
        float hr = sR[0][tid], hi = sI[0][tid];
        for (int ck = 1; ck < NCHUNK; ++ck) {
            float nr = fmaf(lr, hr, fmaf(-li, hi, sR[ck][tid]));
            float ni = fmaf(lr, hi, fmaf(li, hr, sI[ck][tid]));
            hr = nr; hi = ni;
            sR[ck][tid] = hr; sI[ck][tid] = hi;
        }
    }
    __syncthreads();
    for (int i = tid; i < NCHUNK * 64; i += 256) {
        int ck = i >> 6, c = i & 63;
        car[(size_t)ck * N2 + chan0 + c] = sR[ck][c];
        car[(size_t)ck * N2 + N_DIM + chan0 + c] = sI[ck][c];
    }
}

__global__ __launch_bounds__(256) void scan_out_k(const u16* __restrict__ Bu,
                                                  const float* __restrict__ car,
                                                  const float* __restrict__ nu,
                                                  const float* __restrict__ theta,
                                                  u16* __restrict__ Hbf) {
    int idx = blockIdx.x * 256 + threadIdx.x;   // 0 .. NCHUNK*N-1
    int chan = idx & (N_DIM - 1);
    int chunk = idx >> 10;
    float a = expf(nu[chan]), b = expf(theta[chan]);
    float m = expf(-a), s, c;
    __sincosf(b, &s, &c);
    float lr = m * c, li = m * s;
    float hr = 0.f, hi = 0.f;
    if (chunk > 0) {
        size_t cp = (size_t)(chunk - 1) * N2 + chan;
        hr = car[cp]; hi = car[cp + N_DIM];
    }
    size_t base = (size_t)chunk * CHUNK * N2 + chan;
    for (int i = 0; i < CHUNK; ++i) {
        size_t p = base + (size_t)i * N2;
        float br = bf2f(Bu[p]), bi = bf2f(Bu[p + N_DIM]);
        float nr = fmaf(lr, hr, fmaf(-li, hi, br));
        float ni = fmaf(lr, hi, fmaf(li, hr, bi));
        hr = nr; hi = ni;
        Hbf[p] = f2bf(hr);
        Hbf[p + N_DIM] = f2bf(hi);
    }
}

extern "C" void kernel_launch(void* const* d_in, const int* in_sizes, int n_in,
                              void* d_out, int out_size, void* d_ws, size_t ws_size,
                              hipStream_t stream) {
    const float* U     = (const float*)d_in[0];   // [T,H]
    const float* nu    = (const float*)d_in[1];   // [N]
    const float* theta = (const float*)d_in[2];   // [N]
    const float* glog  = (const float*)d_in[3];   // [N]
    const float* Bre   = (const float*)d_in[4];   // [N,H]
    const float* Bim   = (const float*)d_in[5];   // [N,H]
    const float* Cre   = (const float*)d_in[6];   // [H,N]
    const float* Cim   = (const float*)d_in[7];   // [H,N]
    const float* Dp    = (const float*)d_in[8];   // [H]
    float* Y = (float*)d_out;

    u16* Ubf  = (u16*)d_ws;                             // T*H       bf16
    u16* Bcat = Ubf + (size_t)T_DIM * H_DIM;            // 2N*H      bf16
    u16* Ccat = Bcat + (size_t)N2 * H_DIM;              // H*2N      bf16
    u16* Hbf  = Ccat + (size_t)H_DIM * N2;              // T*2N      bf16
    u16* Bu   = Hbf + (size_t)T_DIM * N2;               // T*2N      bf16
    float* car = (float*)(Bu + (size_t)T_DIM * N2);     // NCHUNK*2N f32

    cvt_all_k<<<16384, 256, 0, stream>>>(U, Bre, Bim, glog, Cre, Cim,
                                         Ubf, Bcat, Ccat);

    gemm_pipe<0><<<512, 512, 0, stream>>>(Ubf, Bcat, (void*)Bu, nullptr, nullptr);

    carry_pass_k<<<(NCHUNK * N_DIM) / 256, 256, 0, stream>>>(Bu, nu, theta, car);
    scan_carry_k<<<N_DIM / 64, 256, 0, stream>>>(car, nu, theta);
    scan_out_k<<<(NCHUNK * N_DIM) / 256, 256, 0, stream>>>(Bu, car, nu, theta, Hbf);

    gemm_pipe<1><<<512, 512, 0, stream>>>(Hbf, Ccat, (void*)Y, Dp, Ubf);
}